// Round 8
// baseline (25.361 us; speedup 1.0000x reference)
//
#include <hip/hip_runtime.h>
#include <math.h>

#define NG 2048
#define WIMG 128
#define HIMG 128
#define SEG 16          // compositing segments (= waves per block)
#define RTILE 8         // tile edge (8x8 = 64 px)
#define NTHREADS 1024

// Full per-gaussian projection (exact reference arithmetic).
__device__ __forceinline__ void project_gaussian(
    const float* __restrict__ pos, const float* __restrict__ scales,
    const float* __restrict__ rot, const float* __restrict__ opac,
    const float* __restrict__ view, int i,
    float& depth, float& mux, float& muy,
    float& ic00, float& ic01, float& ic11,
    float& opv, unsigned& bbox)
{
    float qw = rot[4*i+0], qx = rot[4*i+1], qy = rot[4*i+2], qz = rot[4*i+3];
    float nrm = sqrtf(qw*qw + qx*qx + qy*qy + qz*qz) + 1e-8f;
    qw /= nrm; qx /= nrm; qy /= nrm; qz /= nrm;
    float R[3][3];
    R[0][0] = 1.f - 2.f*(qy*qy + qz*qz); R[0][1] = 2.f*(qx*qy + qz*qw); R[0][2] = 2.f*(qx*qz - qy*qw);
    R[1][0] = 2.f*(qx*qy - qz*qw); R[1][1] = 1.f - 2.f*(qx*qx + qz*qz); R[1][2] = 2.f*(qy*qz + qx*qw);
    R[2][0] = 2.f*(qx*qz + qy*qw); R[2][1] = 2.f*(qy*qz - qx*qw); R[2][2] = 1.f - 2.f*(qx*qx + qy*qy);

    float sv[3];
    sv[0] = fmaxf(scales[3*i+0], 1e-6f); sv[0] *= sv[0];
    sv[1] = fmaxf(scales[3*i+1], 1e-6f); sv[1] *= sv[1];
    sv[2] = fmaxf(scales[3*i+2], 1e-6f); sv[2] *= sv[2];

    float C[3][3];
    #pragma unroll
    for (int a = 0; a < 3; ++a)
        #pragma unroll
        for (int b = 0; b < 3; ++b)
            C[a][b] = R[a][0]*sv[0]*R[b][0] + R[a][1]*sv[1]*R[b][1] + R[a][2]*sv[2]*R[b][2];

    float Rv[3][3], tv[3];
    #pragma unroll
    for (int r = 0; r < 3; ++r) {
        Rv[r][0] = view[4*r+0]; Rv[r][1] = view[4*r+1]; Rv[r][2] = view[4*r+2];
        tv[r] = view[4*r+3];
    }
    float Px = pos[3*i], Py = pos[3*i+1], Pz = pos[3*i+2];
    float X = Rv[0][0]*Px + Rv[0][1]*Py + Rv[0][2]*Pz + tv[0];
    float Y = Rv[1][0]*Px + Rv[1][1]*Py + Rv[1][2]*Pz + tv[1];
    float Z = Rv[2][0]*Px + Rv[2][1]*Py + Rv[2][2]*Pz + tv[2];
    depth = Z;

    float valid = (Z > 0.1f) ? 1.f : 0.f;
    float Zs = fmaxf(Z, 1e-6f);
    const float fx = 110.85125168440814f;  // (W/2)/tan(30deg)
    mux = fx * X / Zs + 64.f;
    muy = fx * Y / Zs + 64.f;
    float invZ2 = 1.f / (Zs * Zs);
    float J0[3] = { fx / Zs, 0.f, -fx * X * invZ2 };
    float J1[3] = { 0.f, fx / Zs, -fx * Y * invZ2 };

    float SRt0[3], SRt1[3];
    #pragma unroll
    for (int a = 0; a < 3; ++a) {
        SRt0[a] = C[a][0]*Rv[0][0] + C[a][1]*Rv[0][1] + C[a][2]*Rv[0][2];
        SRt1[a] = C[a][0]*Rv[1][0] + C[a][1]*Rv[1][1] + C[a][2]*Rv[1][2];
    }
    float c00 = J0[0]*SRt0[0] + J0[1]*SRt0[1] + J0[2]*SRt0[2];
    float c01 = J0[0]*SRt1[0] + J0[1]*SRt1[1] + J0[2]*SRt1[2];
    float c11 = J1[0]*SRt1[0] + J1[1]*SRt1[1] + J1[2]*SRt1[2];

    float trc = c00 + c11;
    float det = c00 * c11 - c01 * c01;
    float disc = fmaxf(trc*trc - 4.f*det, 0.f);
    float lam = 0.5f * (trc + sqrtf(disc));
    float rad = 3.f * sqrtf(fmaxf(lam, 1e-8f));
    c00 += 1e-6f; c11 += 1e-6f;
    float det2 = c00 * c11 - c01 * c01 + 1e-8f;
    ic00 = c11 / det2; ic01 = -c01 / det2; ic11 = c00 / det2;
    opv = opac[i] * valid;

    float pxmin = fmaxf(0.f,   truncf(mux - rad));
    float pxmax = fminf(128.f, truncf(mux + rad) + 1.f);
    float pymin = fmaxf(0.f,   truncf(muy - rad));
    float pymax = fminf(128.f, truncf(muy + rad) + 1.f);
    int ixmin = (int)fminf(pxmin, 255.f);
    int ixmax = (int)fmaxf(pxmax, 0.f);
    int iymin = (int)fminf(pymin, 255.f);
    int iymax = (int)fmaxf(pymax, 0.f);
    bbox = (unsigned)ixmin | ((unsigned)ixmax << 8)
         | ((unsigned)iymin << 16) | ((unsigned)iymax << 24);
}

__global__ void __launch_bounds__(NTHREADS)
tile_kernel(const float* __restrict__ pos,
            const float* __restrict__ scales,
            const float* __restrict__ rot,
            const float* __restrict__ colors,
            const float* __restrict__ opac,
            const float* __restrict__ view,
            float* __restrict__ out,
            int N)
{
    __shared__ int    hidx[NG];          // 8 KB unsorted hit indices
    __shared__ float  hdep[NG];          // 8 KB hit depths
    __shared__ int    sidx[NG];          // 8 KB depth-sorted hit indices
    __shared__ float4 part[SEG][64];     // 16 KB partial (R,G,B,T)
    __shared__ int    hcount;

    const int t = threadIdx.x;
    const int wid = t >> 6, lane = t & 63;
    const int tilesX = WIMG / RTILE;
    const int tileX = blockIdx.x % tilesX;
    const int tileY = blockIdx.x / tilesX;
    const int tx0 = tileX * RTILE, tx1 = tx0 + RTILE;
    const int ty0 = tileY * RTILE, ty1 = ty0 + RTILE;

    if (t == 0) hcount = 0;
    __syncthreads();

    // ---- Phase A: CHEAP conservative cull (operator-norm radius bound) ----
    const float fx = 110.85125168440814f;
    const float v00 = view[0], v01 = view[1],  v02 = view[2],  v03 = view[3];
    const float v10 = view[4], v11 = view[5],  v12 = view[6],  v13 = view[7];
    const float v20 = view[8], v21 = view[9],  v22 = view[10], v23 = view[11];

    for (int gb = 0; gb < N; gb += NTHREADS) {
        const int g = gb + t;
        bool hit = false;
        float Z = 0.f;
        if (g < N) {
            float Px = pos[3*g], Py = pos[3*g+1], Pz = pos[3*g+2];
            Z = v20*Px + v21*Py + v22*Pz + v23;
            if (Z > 0.1f) {              // Z<=0.1 => op=0 => exact no-op
                float X = v00*Px + v01*Py + v02*Pz + v03;
                float Y = v10*Px + v11*Py + v12*Pz + v13;
                float invZ = 1.f / Z;
                float mux = fx * X * invZ + 64.f;
                float muy = fx * Y * invZ + 64.f;
                float a = fx * invZ;
                float b = -fx * X * invZ * invZ;
                float c = -fx * Y * invZ * invZ;
                float s0 = scales[3*g], s1 = scales[3*g+1], s2 = scales[3*g+2];
                float smax = fmaxf(fmaxf(fmaxf(s0, s1), s2), 1e-6f);
                // lam_max(cov2d) <= (2a^2+b^2+c^2) * smax^2  (JWSWtJt norm bound)
                float rbar = 3.f * smax * sqrtf(2.f*a*a + b*b + c*c) * 1.05f + 3.2e-4f;
                // +-1 px slack absorbs trunc/clamp/ulp differences
                hit = (mux - rbar < (float)tx1 + 1.f) && (mux + rbar > (float)tx0 - 1.f)
                   && (muy - rbar < (float)ty1 + 1.f) && (muy + rbar > (float)ty0 - 1.f);
            }
        }
        unsigned long long m = __ballot(hit);
        int cnt = __popcll(m);
        int base = 0;
        if (lane == 0) base = atomicAdd(&hcount, cnt);
        base = __shfl(base, 0);
        if (hit) {
            int off = __popcll(m & ((1ull << lane) - 1ull));
            hidx[base + off] = g;
            hdep[base + off] = Z;
        }
    }
    __syncthreads();
    const int K = hcount;

    // ---- Phase A2: sort by (depth desc, idx asc); wave-parallel rank ----
    for (int h = wid; h < K; h += SEG) {
        const float dh = hdep[h];
        const int   ih = hidx[h];
        int r = 0;
        for (int j = lane; j < K; j += 64) {
            float dj = hdep[j];
            r += (dj > dh) || (dj == dh && hidx[j] < ih);
        }
        #pragma unroll
        for (int off = 32; off; off >>= 1) r += __shfl_xor(r, off);
        if (lane == 0) sidx[r] = ih;
    }
    __syncthreads();

    // ---- Phase B: composite sorted hits, 16 segments (exact arithmetic) ----
    const int x = tx0 + (lane & (RTILE - 1));
    const int y = ty0 + (lane / RTILE);
    const float fpx = (float)x, fpy = (float)y;

    const int chunk = (K + SEG - 1) / SEG;
    const int k0 = wid * chunk;
    const int k1 = min(k0 + chunk, K);

    float T = 1.f, aR = 0.f, aG = 0.f, aB = 0.f;

    for (int base = k0; base < k1; base += 64) {
        const int cnt = min(64, k1 - base);
        float mux = 0.f, muy = 0.f, i00 = 0.f, i01 = 0.f, i11 = 0.f, opv = 0.f;
        float c0 = 0.f, c1 = 0.f, c2 = 0.f, depth;
        unsigned bb = 0;
        if (lane < cnt) {
            const int g = sidx[base + lane];
            project_gaussian(pos, scales, rot, opac, view, g,
                             depth, mux, muy, i00, i01, i11, opv, bb);
            c0 = colors[3*g+0]; c1 = colors[3*g+1]; c2 = colors[3*g+2];
        }
        for (int b = 0; b < cnt; ++b) {
            float bmux = __shfl(mux, b), bmuy = __shfl(muy, b);
            float b00 = __shfl(i00, b), b01 = __shfl(i01, b), b11 = __shfl(i11, b);
            float bop = __shfl(opv, b);
            float bc0 = __shfl(c0, b), bc1 = __shfl(c1, b), bc2 = __shfl(c2, b);
            unsigned bbb = __shfl(bb, b);
            int xmin = bbb & 255, xmax = (bbb >> 8) & 255;
            int ymin = (bbb >> 16) & 255, ymax = bbb >> 24;
            bool inside = (x >= xmin) && (x < xmax) && (y >= ymin) && (y < ymax);
            float dx = fpx - bmux, dy = fpy - bmuy;
            float e = -0.5f * (b00*dx*dx + 2.f*b01*dx*dy + b11*dy*dy);
            float G = __expf(fminf(e, 0.f));
            float alpha = inside ? (bop * G) : 0.f;
            float w = alpha * T;
            aR += w * bc0;
            aG += w * bc1;
            aB += w * bc2;
            T *= (1.f - alpha);
        }
    }

    part[wid][lane] = make_float4(aR, aG, aB, T);
    __syncthreads();

    if (t < 64) {
        float accR = 0.f, accG = 0.f, accB = 0.f, Tacc = 1.f;
        #pragma unroll
        for (int s = 0; s < SEG; ++s) {
            float4 p = part[s][t];
            accR += Tacc * p.x;
            accG += Tacc * p.y;
            accB += Tacc * p.z;
            Tacc *= p.w;
        }
        int xx = tx0 + (t & (RTILE - 1));
        int yy = ty0 + (t / RTILE);
        int idx = (yy * WIMG + xx) * 3;
        out[idx+0] = accR;
        out[idx+1] = accG;
        out[idx+2] = accB;
    }
}

extern "C" void kernel_launch(void* const* d_in, const int* in_sizes, int n_in,
                              void* d_out, int out_size, void* d_ws, size_t ws_size,
                              hipStream_t stream) {
    const float* pos    = (const float*)d_in[0];
    const float* scales = (const float*)d_in[1];
    const float* rot    = (const float*)d_in[2];
    const float* colors = (const float*)d_in[3];
    const float* opac   = (const float*)d_in[4];
    const float* view   = (const float*)d_in[5];
    float* out = (float*)d_out;
    const int N = in_sizes[4];    // opacities count

    const int nTiles = (WIMG / RTILE) * (HIMG / RTILE);   // 256 blocks
    tile_kernel<<<nTiles, NTHREADS, 0, stream>>>(
        pos, scales, rot, colors, opac, view, out, N);
}

// Round 9
// 15.964 us; speedup vs baseline: 1.5886x; 1.5886x over previous
//
#include <hip/hip_runtime.h>
#include <math.h>

#define NG 2048
#define WIMG 128
#define HIMG 128
#define REC 12          // floats per gaussian record (3 x float4)
#define SEG 16          // compositing segments per tile (= waves per block)
#define RTILE 8         // render tile edge (8x8 = 64 px = 1 wave)
#define GPB 4           // gaussians per preprocess block (1 wave each)

// Workspace layout:
//   srec    : NG * REC floats (96 KiB)  — sorted records, 3 x float4 each
//   bboxArr : NG u32 (8 KiB)            — sorted packed bboxes (u8x4)
// Record layout (12 floats = 3 float4):
// r0: mux, muy, ic00, ic01
// r1: ic11, op,  c0,   c1
// r2: c2,  depth, pad, pad

__global__ void __launch_bounds__(256)
preprocess_kernel(const float* __restrict__ pos,
                  const float* __restrict__ scales,
                  const float* __restrict__ rot,
                  const float* __restrict__ colors,
                  const float* __restrict__ opac,
                  const float* __restrict__ view,
                  float* __restrict__ srec,
                  unsigned* __restrict__ bboxArr,
                  int N)
{
    __shared__ float zs[NG];       // 8 KB camera-space depths
    const int t = threadIdx.x;

    // depths straight from global pos (L2-hot) — identical expression in
    // every block => bitwise-consistent ranks chip-wide
    const float Rv20 = view[8], Rv21 = view[9], Rv22 = view[10], tv2 = view[11];
    for (int j = t; j < N; j += 256) {
        zs[j] = Rv20 * pos[3*j] + Rv21 * pos[3*j+1] + Rv22 * pos[3*j+2] + tv2;
    }
    __syncthreads();

    const int wid = t >> 6, lane = t & 63;
    const int i = blockIdx.x * GPB + wid;
    if (i >= N) return;

    // ---- rank (descending depth, stable), split across 64 lanes ----
    const float di = zs[i];
    int cnt = 0;
    for (int j = lane; j < N; j += 64) {
        float dj = zs[j];
        cnt += (dj > di) || (dj == di && j < i);
    }
    #pragma unroll
    for (int off = 32; off; off >>= 1) cnt += __shfl_xor(cnt, off);
    const int rank = cnt;   // all lanes agree

    // ---- per-gaussian math (redundant on all lanes; no divergence) ----
    float qw = rot[4*i+0], qx = rot[4*i+1], qy = rot[4*i+2], qz = rot[4*i+3];
    float nrm = sqrtf(qw*qw + qx*qx + qy*qy + qz*qz) + 1e-8f;
    qw /= nrm; qx /= nrm; qy /= nrm; qz /= nrm;
    float R[3][3];
    R[0][0] = 1.f - 2.f*(qy*qy + qz*qz); R[0][1] = 2.f*(qx*qy + qz*qw); R[0][2] = 2.f*(qx*qz - qy*qw);
    R[1][0] = 2.f*(qx*qy - qz*qw); R[1][1] = 1.f - 2.f*(qx*qx + qz*qz); R[1][2] = 2.f*(qy*qz + qx*qw);
    R[2][0] = 2.f*(qx*qz + qy*qw); R[2][1] = 2.f*(qy*qz - qx*qw); R[2][2] = 1.f - 2.f*(qx*qx + qy*qy);

    float sv[3];
    sv[0] = fmaxf(scales[3*i+0], 1e-6f); sv[0] *= sv[0];
    sv[1] = fmaxf(scales[3*i+1], 1e-6f); sv[1] *= sv[1];
    sv[2] = fmaxf(scales[3*i+2], 1e-6f); sv[2] *= sv[2];

    float C[3][3];
    #pragma unroll
    for (int a = 0; a < 3; ++a)
        #pragma unroll
        for (int b = 0; b < 3; ++b)
            C[a][b] = R[a][0]*sv[0]*R[b][0] + R[a][1]*sv[1]*R[b][1] + R[a][2]*sv[2]*R[b][2];

    float Rv[3][3], tv[3];
    #pragma unroll
    for (int r = 0; r < 3; ++r) {
        Rv[r][0] = view[4*r+0]; Rv[r][1] = view[4*r+1]; Rv[r][2] = view[4*r+2];
        tv[r] = view[4*r+3];
    }
    float Px = pos[3*i], Py = pos[3*i+1], Pz = pos[3*i+2];
    float X = Rv[0][0]*Px + Rv[0][1]*Py + Rv[0][2]*Pz + tv[0];
    float Y = Rv[1][0]*Px + Rv[1][1]*Py + Rv[1][2]*Pz + tv[1];
    float Z = di;

    float valid = (Z > 0.1f) ? 1.f : 0.f;
    float Zs = fmaxf(Z, 1e-6f);
    const float fx = 110.85125168440814f;  // (W/2)/tan(30deg)
    float mux = fx * X / Zs + 64.f;
    float muy = fx * Y / Zs + 64.f;
    float invZ2 = 1.f / (Zs * Zs);
    float J0[3] = { fx / Zs, 0.f, -fx * X * invZ2 };
    float J1[3] = { 0.f, fx / Zs, -fx * Y * invZ2 };

    float SRt0[3], SRt1[3];
    #pragma unroll
    for (int a = 0; a < 3; ++a) {
        SRt0[a] = C[a][0]*Rv[0][0] + C[a][1]*Rv[0][1] + C[a][2]*Rv[0][2];
        SRt1[a] = C[a][0]*Rv[1][0] + C[a][1]*Rv[1][1] + C[a][2]*Rv[1][2];
    }
    float c00 = J0[0]*SRt0[0] + J0[1]*SRt0[1] + J0[2]*SRt0[2];
    float c01 = J0[0]*SRt1[0] + J0[1]*SRt1[1] + J0[2]*SRt1[2];
    float c11 = J1[0]*SRt1[0] + J1[1]*SRt1[1] + J1[2]*SRt1[2];

    float trc = c00 + c11;
    float det = c00 * c11 - c01 * c01;
    float disc = fmaxf(trc*trc - 4.f*det, 0.f);
    float lam = 0.5f * (trc + sqrtf(disc));
    float rad = 3.f * sqrtf(fmaxf(lam, 1e-8f));
    c00 += 1e-6f; c11 += 1e-6f;
    float det2 = c00 * c11 - c01 * c01 + 1e-8f;
    float ic00 = c11 / det2, ic01 = -c01 / det2, ic11 = c00 / det2;
    float opv = opac[i] * valid;

    float pxmin = fmaxf(0.f,   truncf(mux - rad));
    float pxmax = fminf(128.f, truncf(mux + rad) + 1.f);
    float pymin = fmaxf(0.f,   truncf(muy - rad));
    float pymax = fminf(128.f, truncf(muy + rad) + 1.f);

    int ixmin = (int)fminf(pxmin, 255.f);
    int ixmax = (int)fmaxf(pxmax, 0.f);
    int iymin = (int)fminf(pymin, 255.f);
    int iymax = (int)fmaxf(pymax, 0.f);
    unsigned int bbox = (unsigned)ixmin | ((unsigned)ixmax << 8)
                      | ((unsigned)iymin << 16) | ((unsigned)iymax << 24);

    if (lane == 0) {
        float4* o = (float4*)(srec + (size_t)rank * REC);
        o[0] = make_float4(mux, muy, ic00, ic01);
        o[1] = make_float4(ic11, opv, colors[3*i+0], colors[3*i+1]);
        o[2] = make_float4(colors[3*i+2], di, 0.f, 0.f);
        bboxArr[rank] = bbox;
    }
}

__global__ void __launch_bounds__(1024)
render_kernel(const float* __restrict__ srec,
              const unsigned* __restrict__ bboxArr,
              float* __restrict__ out, int N)
{
    __shared__ float4 part[SEG][64];   // 4 KB partial (R,G,B,T) per segment x pixel
    const int t    = threadIdx.x;
    const int lane = t & 63;           // pixel within 8x8 tile AND gaussian-lane
    const int seg  = t >> 6;           // segment id = wave id
    const int tilesX = WIMG / RTILE;
    const int tileX = blockIdx.x % tilesX;
    const int tileY = blockIdx.x / tilesX;
    const int x = tileX * RTILE + (lane & (RTILE - 1));
    const int y = tileY * RTILE + (lane / RTILE);
    const float fpx = (float)x, fpy = (float)y;
    const int tx0 = tileX * RTILE, tx1 = tx0 + RTILE;
    const int ty0 = tileY * RTILE, ty1 = ty0 + RTILE;

    const int chunk = (N + SEG - 1) / SEG;   // 128 for N=2048
    const int k0 = seg * chunk;
    const int k1 = min(k0 + chunk, N);

    float T = 1.f, aR = 0.f, aG = 0.f, aB = 0.f;
    const float4* rec = (const float4*)srec;

    for (int base = k0; base < k1; base += 64) {
        const int g = base + lane;        // lane acts as gaussian index
        bool hit = false;
        if (g < k1) {
            unsigned bb = bboxArr[g];     // 4-byte scan (vs 48-byte record)
            int xmin = bb & 255, xmax = (bb >> 8) & 255;
            int ymin = (bb >> 16) & 255, ymax = bb >> 24;
            hit = (xmin < tx1) && (xmax > tx0) && (ymin < ty1) && (ymax > ty0);
        }
        unsigned long long m = __ballot(hit);
        while (m) {
            const int b = __ffsll((long long)m) - 1;   // ascending = depth order
            m &= m - 1;
            const int gb = base + b;      // wave-uniform (b is from SGPR mask)
            // uniform address -> compiler emits scalar s_load (no shfl chain)
            float4 r0 = rec[gb*3+0];      // mux, muy, ic00, ic01
            float4 r1 = rec[gb*3+1];      // ic11, op, c0, c1
            float4 r2 = rec[gb*3+2];      // c2, depth, pad, pad
            unsigned bbb = bboxArr[gb];
            int xmin = bbb & 255, xmax = (bbb >> 8) & 255;
            int ymin = (bbb >> 16) & 255, ymax = bbb >> 24;
            bool inside = (x >= xmin) && (x < xmax) && (y >= ymin) && (y < ymax);
            float dx = fpx - r0.x, dy = fpy - r0.y;
            float e = -0.5f * (r0.z*dx*dx + 2.f*r0.w*dx*dy + r1.x*dy*dy);
            float G = __expf(fminf(e, 0.f));
            float alpha = inside ? (r1.y * G) : 0.f;
            float w = alpha * T;
            aR += w * r1.z;
            aG += w * r1.w;
            aB += w * r2.x;
            T *= (1.f - alpha);
        }
    }

    part[seg][lane] = make_float4(aR, aG, aB, T);
    __syncthreads();

    if (t < 64) {
        float accR = 0.f, accG = 0.f, accB = 0.f, Tacc = 1.f;
        #pragma unroll
        for (int s = 0; s < SEG; ++s) {
            float4 p = part[s][t];
            accR += Tacc * p.x;
            accG += Tacc * p.y;
            accB += Tacc * p.z;
            Tacc *= p.w;
        }
        int idx = (y * WIMG + x) * 3;
        out[idx+0] = accR;
        out[idx+1] = accG;
        out[idx+2] = accB;
    }
}

extern "C" void kernel_launch(void* const* d_in, const int* in_sizes, int n_in,
                              void* d_out, int out_size, void* d_ws, size_t ws_size,
                              hipStream_t stream) {
    const float* pos    = (const float*)d_in[0];
    const float* scales = (const float*)d_in[1];
    const float* rot    = (const float*)d_in[2];
    const float* colors = (const float*)d_in[3];
    const float* opac   = (const float*)d_in[4];
    const float* view   = (const float*)d_in[5];
    float* out = (float*)d_out;
    float* srec = (float*)d_ws;                       // 96 KiB
    unsigned* bboxArr = (unsigned*)(srec + NG * REC); // 8 KiB
    const int N = in_sizes[4];    // opacities count

    const int nPreBlocks = (N + GPB - 1) / GPB;   // 512 blocks
    preprocess_kernel<<<nPreBlocks, 256, 0, stream>>>(
        pos, scales, rot, colors, opac, view, srec, bboxArr, N);

    const int nTiles = (WIMG / RTILE) * (HIMG / RTILE);   // 256 blocks
    render_kernel<<<nTiles, 1024, 0, stream>>>(srec, bboxArr, out, N);
}